// Round 2
// baseline (1028.365 us; speedup 1.0000x reference)
//
#include <hip/hip_runtime.h>
#include <hip/hip_bf16.h>

#define NVOX (256*256*32)   // 2,097,152
#define CC 64
#define HH 480
#define WW 640
#define HWTOT (HH*WW)

typedef float vfloat4 __attribute__((ext_vector_type(4)));
typedef int   vint4   __attribute__((ext_vector_type(4)));

// ---------------- Kernel 1: per-voxel weight + feat index ----------------
__global__ __launch_bounds__(256) void weight_kernel(
    const int*   __restrict__ pp,      // (N,2) int32
    const int*   __restrict__ scale_p, // scalar
    const int*   __restrict__ mask,    // (N,) int32 (bool)
    const float* __restrict__ pix_z,   // (N,)
    const float* __restrict__ depth,   // (H*W,)
    int*         __restrict__ feat_out,// (N,)
    float*       __restrict__ w_out)   // (N,)
{
    int t = blockIdx.x * blockDim.x + threadIdx.x;   // handles voxels 4t..4t+3
    if (t * 4 >= NVOX) return;
    int scale = scale_p[0];

    vint4 pp0 = ((const vint4*)pp)[t*2+0];   // (x0,y0,x1,y1)
    vint4 pp1 = ((const vint4*)pp)[t*2+1];   // (x2,y2,x3,y3)
    vint4 m4  = ((const vint4*)mask)[t];
    vfloat4 z4 = ((const vfloat4*)pix_z)[t];

    int   px[4] = {pp0.x, pp0.z, pp1.x, pp1.z};
    int   py[4] = {pp0.y, pp0.w, pp1.y, pp1.w};
    int   mm[4] = {m4.x, m4.y, m4.z, m4.w};
    float zz[4] = {z4.x, z4.y, z4.z, z4.w};

    int fi[4]; float wv[4];
#pragma unroll
    for (int j = 0; j < 4; ++j) {
        int sx = px[j], sy = py[j];
        if (scale != 1) { sx = px[j] / scale; sy = py[j] / scale; }
        int feat = sy * WW + sx;
        bool fov = (mm[j] != 0);
        float d = fov ? depth[py[j] * WW + px[j]] : 0.0f;
        float diff = zz[j] - d;
        float gw = __expf(-0.5f * diff * diff);
        float w = (d == 0.0f) ? 1.0f : gw;
        wv[j] = fov ? w : 0.0f;
        fi[j] = fov ? feat : 0;   // masked lanes gather addr 0 (broadcast, free)
    }
    vint4 fo;  fo.x=fi[0]; fo.y=fi[1]; fo.z=fi[2]; fo.w=fi[3];
    vfloat4 wo; wo.x=wv[0]; wo.y=wv[1]; wo.z=wv[2]; wo.w=wv[3];
    ((vint4*)feat_out)[t] = fo;
    ((vfloat4*)w_out)[t]  = wo;
}

// ---------------- Kernel 2: gather-scale-write, 4 voxels x 4 channels ----------------
__global__ __launch_bounds__(256) void scatter_kernel(
    const float* __restrict__ x2d,      // (C,H,W)
    const int*   __restrict__ feat_idx, // (N,)
    const float* __restrict__ wgt,      // (N,)
    float*       __restrict__ out)      // (C,N)
{
    int t = blockIdx.x * blockDim.x + threadIdx.x;   // voxel quad index
    long i0 = (long)t * 4;
    int cg = blockIdx.y * 4;

    vint4   f4 = __builtin_nontemporal_load((const vint4*)feat_idx + t);
    vfloat4 w4 = __builtin_nontemporal_load((const vfloat4*)wgt + t);

#pragma unroll
    for (int g = 0; g < 4; ++g) {
        int c = cg + g;
        const float* base = x2d + (long)c * HWTOT;
        vfloat4 v;
        v.x = base[f4.x] * w4.x;
        v.y = base[f4.y] * w4.y;
        v.z = base[f4.z] * w4.z;
        v.w = base[f4.w] * w4.w;
        __builtin_nontemporal_store(v, (vfloat4*)(out + (long)c * NVOX + i0));
    }
}

// ---------------- Fallback: fused (if workspace too small) ----------------
__global__ __launch_bounds__(256) void fused_kernel(
    const float* __restrict__ x2d,
    const int*   __restrict__ pp,
    const int*   __restrict__ scale_p,
    const int*   __restrict__ mask,
    const float* __restrict__ pix_z,
    const float* __restrict__ depth,
    float*       __restrict__ out)
{
    int t = blockIdx.x * blockDim.x + threadIdx.x;
    long i0 = (long)t * 4;
    int cg = blockIdx.y * 4;
    int scale = scale_p[0];

    vint4 pp0 = ((const vint4*)pp)[t*2+0];
    vint4 pp1 = ((const vint4*)pp)[t*2+1];
    vint4 m4  = ((const vint4*)mask)[t];
    vfloat4 z4 = ((const vfloat4*)pix_z)[t];

    int   px[4] = {pp0.x, pp0.z, pp1.x, pp1.z};
    int   py[4] = {pp0.y, pp0.w, pp1.y, pp1.w};
    int   mm[4] = {m4.x, m4.y, m4.z, m4.w};
    float zz[4] = {z4.x, z4.y, z4.z, z4.w};

    int fi[4]; float wv[4];
#pragma unroll
    for (int j = 0; j < 4; ++j) {
        int sx = px[j], sy = py[j];
        if (scale != 1) { sx = px[j] / scale; sy = py[j] / scale; }
        int feat = sy * WW + sx;
        bool fov = (mm[j] != 0);
        float d = fov ? depth[py[j] * WW + px[j]] : 0.0f;
        float diff = zz[j] - d;
        float gw = __expf(-0.5f * diff * diff);
        float w = (d == 0.0f) ? 1.0f : gw;
        wv[j] = fov ? w : 0.0f;
        fi[j] = fov ? feat : 0;
    }

#pragma unroll
    for (int g = 0; g < 4; ++g) {
        int c = cg + g;
        const float* base = x2d + (long)c * HWTOT;
        vfloat4 v;
        v.x = base[fi[0]] * wv[0];
        v.y = base[fi[1]] * wv[1];
        v.z = base[fi[2]] * wv[2];
        v.w = base[fi[3]] * wv[3];
        __builtin_nontemporal_store(v, (vfloat4*)(out + (long)c * NVOX + i0));
    }
}

extern "C" void kernel_launch(void* const* d_in, const int* in_sizes, int n_in,
                              void* d_out, int out_size, void* d_ws, size_t ws_size,
                              hipStream_t stream) {
    const float* x2d     = (const float*)d_in[0];
    const int*   pp      = (const int*)d_in[1];
    const int*   scale_p = (const int*)d_in[2];
    const int*   mask    = (const int*)d_in[3];
    const float* pix_z   = (const float*)d_in[4];
    const float* depth   = (const float*)d_in[5];
    float*       out     = (float*)d_out;

    const int nquad = NVOX / 4;              // 524,288 threads
    dim3 blk(256);
    dim3 grid1(nquad / 256);                 // 2048 blocks
    dim3 grid2(nquad / 256, CC / 4);         // (2048, 16)

    size_t need = (size_t)NVOX * (sizeof(int) + sizeof(float));  // 16.8 MB
    if (ws_size >= need) {
        int*   feat_ws = (int*)d_ws;
        float* w_ws    = (float*)((char*)d_ws + (size_t)NVOX * sizeof(int));
        weight_kernel<<<grid1, blk, 0, stream>>>(pp, scale_p, mask, pix_z, depth,
                                                 feat_ws, w_ws);
        scatter_kernel<<<grid2, blk, 0, stream>>>(x2d, feat_ws, w_ws, out);
    } else {
        fused_kernel<<<grid2, blk, 0, stream>>>(x2d, pp, scale_p, mask, pix_z,
                                                depth, out);
    }
}

// Round 3
// 662.306 us; speedup vs baseline: 1.5527x; 1.5527x over previous
//
#include <hip/hip_runtime.h>
#include <hip/hip_bf16.h>

#define NVOX (256*256*32)   // 2,097,152
#define CC 64
#define HH 480
#define WW 640
#define HWTOT (HH*WW)        // 307,200 pixels

typedef float vfloat4 __attribute__((ext_vector_type(4)));
typedef int   vint4   __attribute__((ext_vector_type(4)));

// ---------------- Kernel 1: per-voxel weight + feat index ----------------
__global__ __launch_bounds__(256) void weight_kernel(
    const int*   __restrict__ pp,      // (N,2) int32
    const int*   __restrict__ scale_p, // scalar
    const int*   __restrict__ mask,    // (N,) int32 (bool)
    const float* __restrict__ pix_z,   // (N,)
    const float* __restrict__ depth,   // (H*W,)
    int*         __restrict__ feat_out,// (N,)
    float*       __restrict__ w_out)   // (N,)
{
    int t = blockIdx.x * blockDim.x + threadIdx.x;   // handles voxels 4t..4t+3
    if (t * 4 >= NVOX) return;
    int scale = scale_p[0];

    vint4 pp0 = ((const vint4*)pp)[t*2+0];   // (x0,y0,x1,y1)
    vint4 pp1 = ((const vint4*)pp)[t*2+1];   // (x2,y2,x3,y3)
    vint4 m4  = ((const vint4*)mask)[t];
    vfloat4 z4 = ((const vfloat4*)pix_z)[t];

    int   px[4] = {pp0.x, pp0.z, pp1.x, pp1.z};
    int   py[4] = {pp0.y, pp0.w, pp1.y, pp1.w};
    int   mm[4] = {m4.x, m4.y, m4.z, m4.w};
    float zz[4] = {z4.x, z4.y, z4.z, z4.w};

    int fi[4]; float wv[4];
#pragma unroll
    for (int j = 0; j < 4; ++j) {
        int sx = px[j], sy = py[j];
        if (scale != 1) { sx = px[j] / scale; sy = py[j] / scale; }
        int feat = sy * WW + sx;
        bool fov = (mm[j] != 0);
        float d = fov ? depth[py[j] * WW + px[j]] : 0.0f;
        float diff = zz[j] - d;
        float gw = __expf(-0.5f * diff * diff);
        float w = (d == 0.0f) ? 1.0f : gw;
        wv[j] = fov ? w : 0.0f;
        fi[j] = fov ? feat : 0;   // masked lanes gather addr 0 (broadcast, free)
    }
    vint4 fo;  fo.x=fi[0]; fo.y=fi[1]; fo.z=fi[2]; fo.w=fi[3];
    vfloat4 wo; wo.x=wv[0]; wo.y=wv[1]; wo.z=wv[2]; wo.w=wv[3];
    ((vint4*)feat_out)[t] = fo;
    ((vfloat4*)w_out)[t]  = wo;
}

// ---------------- Kernel 2: transpose x2d (C,H,W) -> xT (H*W, C) ----------------
__global__ __launch_bounds__(256) void transpose_kernel(
    const float* __restrict__ x2d,   // (C, HWTOT)
    float*       __restrict__ xT)    // (HWTOT, C)
{
    __shared__ float tile[64][65];   // +1 pad: stride 65 mod 32 == 1, conflict-free
    int t  = threadIdx.x;
    int p0 = blockIdx.x * 64;

    // load 64x64 tile: consecutive lanes -> consecutive pixels (coalesced)
#pragma unroll
    for (int k = 0; k < 16; ++k) {
        int c = k * 4 + (t >> 6);    // 0..63
        int p = t & 63;
        tile[c][p] = x2d[(long)c * HWTOT + p0 + p];
    }
    __syncthreads();
    // write: consecutive lanes -> consecutive channels (coalesced)
#pragma unroll
    for (int k = 0; k < 16; ++k) {
        int p = k * 4 + (t >> 6);
        int c = t & 63;
        xT[(long)(p0 + p) * CC + c] = tile[c][p];
    }
}

// ---------------- Kernel 3: per-voxel contiguous gather, all 64 channels ----------------
__global__ __launch_bounds__(256) void gather64_kernel(
    const float* __restrict__ xT,       // (HWTOT, 64)
    const int*   __restrict__ feat_idx, // (N,)
    const float* __restrict__ wgt,      // (N,)
    float*       __restrict__ out)      // (C, N)
{
    int i = blockIdx.x * blockDim.x + threadIdx.x;   // voxel index
    int fi  = __builtin_nontemporal_load(feat_idx + i);
    float w = __builtin_nontemporal_load(wgt + i);

    const vfloat4* src = (const vfloat4*)(xT + (long)fi * CC);  // 256B aligned block
    float* op = out + i;

#pragma unroll
    for (int g = 0; g < 16; ++g) {
        vfloat4 v = src[g];
        v.x *= w; v.y *= w; v.z *= w; v.w *= w;
        __builtin_nontemporal_store(v.x, op + (long)(4*g + 0) * NVOX);
        __builtin_nontemporal_store(v.y, op + (long)(4*g + 1) * NVOX);
        __builtin_nontemporal_store(v.z, op + (long)(4*g + 2) * NVOX);
        __builtin_nontemporal_store(v.w, op + (long)(4*g + 3) * NVOX);
    }
}

// ---------------- Mid fallback: gather-scale-write, 4 voxels x 4 channels ----------------
__global__ __launch_bounds__(256) void scatter_kernel(
    const float* __restrict__ x2d,
    const int*   __restrict__ feat_idx,
    const float* __restrict__ wgt,
    float*       __restrict__ out)
{
    int t = blockIdx.x * blockDim.x + threadIdx.x;
    long i0 = (long)t * 4;
    int cg = blockIdx.y * 4;

    vint4   f4 = __builtin_nontemporal_load((const vint4*)feat_idx + t);
    vfloat4 w4 = __builtin_nontemporal_load((const vfloat4*)wgt + t);

#pragma unroll
    for (int g = 0; g < 4; ++g) {
        int c = cg + g;
        const float* base = x2d + (long)c * HWTOT;
        vfloat4 v;
        v.x = base[f4.x] * w4.x;
        v.y = base[f4.y] * w4.y;
        v.z = base[f4.z] * w4.z;
        v.w = base[f4.w] * w4.w;
        __builtin_nontemporal_store(v, (vfloat4*)(out + (long)c * NVOX + i0));
    }
}

// ---------------- Last fallback: fully fused ----------------
__global__ __launch_bounds__(256) void fused_kernel(
    const float* __restrict__ x2d,
    const int*   __restrict__ pp,
    const int*   __restrict__ scale_p,
    const int*   __restrict__ mask,
    const float* __restrict__ pix_z,
    const float* __restrict__ depth,
    float*       __restrict__ out)
{
    int t = blockIdx.x * blockDim.x + threadIdx.x;
    long i0 = (long)t * 4;
    int cg = blockIdx.y * 4;
    int scale = scale_p[0];

    vint4 pp0 = ((const vint4*)pp)[t*2+0];
    vint4 pp1 = ((const vint4*)pp)[t*2+1];
    vint4 m4  = ((const vint4*)mask)[t];
    vfloat4 z4 = ((const vfloat4*)pix_z)[t];

    int   px[4] = {pp0.x, pp0.z, pp1.x, pp1.z};
    int   py[4] = {pp0.y, pp0.w, pp1.y, pp1.w};
    int   mm[4] = {m4.x, m4.y, m4.z, m4.w};
    float zz[4] = {z4.x, z4.y, z4.z, z4.w};

    int fi[4]; float wv[4];
#pragma unroll
    for (int j = 0; j < 4; ++j) {
        int sx = px[j], sy = py[j];
        if (scale != 1) { sx = px[j] / scale; sy = py[j] / scale; }
        int feat = sy * WW + sx;
        bool fov = (mm[j] != 0);
        float d = fov ? depth[py[j] * WW + px[j]] : 0.0f;
        float diff = zz[j] - d;
        float gw = __expf(-0.5f * diff * diff);
        float w = (d == 0.0f) ? 1.0f : gw;
        wv[j] = fov ? w : 0.0f;
        fi[j] = fov ? feat : 0;
    }

#pragma unroll
    for (int g = 0; g < 4; ++g) {
        int c = cg + g;
        const float* base = x2d + (long)c * HWTOT;
        vfloat4 v;
        v.x = base[fi[0]] * wv[0];
        v.y = base[fi[1]] * wv[1];
        v.z = base[fi[2]] * wv[2];
        v.w = base[fi[3]] * wv[3];
        __builtin_nontemporal_store(v, (vfloat4*)(out + (long)c * NVOX + i0));
    }
}

extern "C" void kernel_launch(void* const* d_in, const int* in_sizes, int n_in,
                              void* d_out, int out_size, void* d_ws, size_t ws_size,
                              hipStream_t stream) {
    const float* x2d     = (const float*)d_in[0];
    const int*   pp      = (const int*)d_in[1];
    const int*   scale_p = (const int*)d_in[2];
    const int*   mask    = (const int*)d_in[3];
    const float* pix_z   = (const float*)d_in[4];
    const float* depth   = (const float*)d_in[5];
    float*       out     = (float*)d_out;

    const int nquad = NVOX / 4;
    dim3 blk(256);

    size_t need_meta = (size_t)NVOX * 8;                         // feat + w: 16.8 MB
    size_t need_full = need_meta + (size_t)HWTOT * CC * 4;       // + xT: 95.4 MB

    if (ws_size >= need_full) {
        int*   feat_ws = (int*)d_ws;
        float* w_ws    = (float*)((char*)d_ws + (size_t)NVOX * 4);
        float* xT      = (float*)((char*)d_ws + need_meta);
        weight_kernel<<<dim3(nquad/256), blk, 0, stream>>>(pp, scale_p, mask,
                                                           pix_z, depth, feat_ws, w_ws);
        transpose_kernel<<<dim3(HWTOT/64), blk, 0, stream>>>(x2d, xT);
        gather64_kernel<<<dim3(NVOX/256), blk, 0, stream>>>(xT, feat_ws, w_ws, out);
    } else if (ws_size >= need_meta) {
        int*   feat_ws = (int*)d_ws;
        float* w_ws    = (float*)((char*)d_ws + (size_t)NVOX * 4);
        weight_kernel<<<dim3(nquad/256), blk, 0, stream>>>(pp, scale_p, mask,
                                                           pix_z, depth, feat_ws, w_ws);
        scatter_kernel<<<dim3(nquad/256, CC/4), blk, 0, stream>>>(x2d, feat_ws, w_ws, out);
    } else {
        fused_kernel<<<dim3(nquad/256, CC/4), blk, 0, stream>>>(x2d, pp, scale_p,
                                                                mask, pix_z, depth, out);
    }
}